// Round 1
// baseline (29223.294 us; speedup 1.0000x reference)
//
#include <hip/hip_runtime.h>
#include <hip/hip_cooperative_groups.h>
#include <math.h>

namespace cg = cooperative_groups;

#define D 256
#define NH 4
#define HDIM 64
#define FFD 2048
#define NL 3
#define VOC 30000
#define BPTT 20
#define BATCH 64
#define NMAX (BPTT*BATCH)   /* 1280 */

struct Params {
  const float* image_feats;
  const int*   target;
  const float* emb_table;
  const float* W_g2e;
  const float* b_g2e;
  const float* W_out;
  const float* b_out;
  const float* Wqkv; const float* bqkv;
  const float* Wo;   const float* bo;
  const float* W1;   const float* b1;
  const float* W2;   const float* b2;
  const float* g1;   const float* be1;
  const float* g2;   const float* be2;
  float* out_probs; float* out_words; float* out_eos;
  float* embeds; float* xbuf; float* qkvb; float* obuf; float* pbuf; float* logits;
  int* maskb;
};

// one LDS arena shared by all phases (phases separated by grid.sync / __syncthreads)
union Smem {
  struct { float As[8][256]; float ffs[8][256]; } g;                       // 16 KiB gemm tiles
  struct { float qs[BPTT*HDIM], ks[BPTT*HDIM], vs[BPTT*HDIM],
                 ps[BPTT*(BPTT+1)]; } a;                                   // ~17 KiB attn
  struct { float red[4]; float r_s[4]; float r_em[4]; int r_ei[4]; } v;    // vocab reductions
  float xs[2048];                                                          // img row
};

// C-tile accumulate: acc[j][c] += sum_k As[tokg*2+j][k] * W[k][col+c]
// (identical summation order to the previously-verified k_gemm8 inner loop)
__device__ __forceinline__ void tile_acc(const float (*As)[256], const float* __restrict__ Wp,
                                         int M, int tokg, float acc[2][4]) {
#pragma unroll 2
  for (int kk = 0; kk < 256; kk += 4) {
    float a0[4], a1[4], w[4][4];
    *(float4*)a0 = *(const float4*)&As[tokg*2+0][kk];
    *(float4*)a1 = *(const float4*)&As[tokg*2+1][kk];
#pragma unroll
    for (int q = 0; q < 4; ++q)
      *(float4*)w[q] = *(const float4*)(Wp + (long)(kk+q)*M);
#pragma unroll
    for (int c = 0; c < 4; ++c)
#pragma unroll
      for (int q = 0; q < 4; ++q) {
        acc[0][c] += a0[q]*w[q][c];
        acc[1][c] += a1[q]*w[q][c];
      }
  }
}

__global__ __launch_bounds__(256, 4) void mega(Params p) {
  cg::grid_group grid = cg::this_grid();
  const int wgid = blockIdx.x, nwg = gridDim.x, tid = threadIdx.x;
  const int colg = tid & 63, tokg = tid >> 6;   // 64 col-groups x 4 token-groups
  __shared__ Smem sm;

  // ================= phase 0: mask + img embed =================
  if (wgid == 0 && tid < BATCH) {
    int run = 1;
    for (int j = 0; j < BPTT; ++j) {
      if (j > 0 && p.target[tid*BPTT + j] == 2) run = 0;
      p.maskb[tid*BPTT + j] = run;
    }
  }
  for (int b = wgid; b < BATCH; b += nwg) {
    __syncthreads();
    for (int j = 0; j < 8; ++j) sm.xs[tid + j*256] = p.image_feats[b*2048 + tid + j*256];
    __syncthreads();
    float acc = 0.f;
    for (int k = 0; k < 2048; k += 4) {
      float4 xv = *(const float4*)&sm.xs[k];
      acc += xv.x * p.W_g2e[(k+0)*D + tid];
      acc += xv.y * p.W_g2e[(k+1)*D + tid];
      acc += xv.z * p.W_g2e[(k+2)*D + tid];
      acc += xv.w * p.W_g2e[(k+3)*D + tid];
    }
    p.embeds[b*D + tid] = acc + p.b_g2e[tid];
  }
  grid.sync();

  // ================= decode loop =================
  for (int i = 0; i < BPTT; ++i) {
    const int S = i + 1, N = S * BATCH, ntok8 = N >> 3;

    for (int l = 0; l < NL; ++l) {
      const float* X = (l == 0) ? p.embeds : p.xbuf;

      // ---- A: qkv = X @ Wqkv + bqkv ----
      {
        const float* Wl = p.Wqkv + (long)l*D*3*D;
        const float* bl = p.bqkv + l*3*D;
        const int ntiles = ntok8 * 3;
        for (int t = wgid; t < ntiles; t += nwg) {
          const int tx = t % ntok8, ty = t / ntok8;
          const int tok0 = tx*8, col = ty*256 + colg*4;
          __syncthreads();
#pragma unroll
          for (int j = 0; j < 8; ++j) sm.g.As[j][tid] = X[(long)(tok0+j)*D + tid];
          __syncthreads();
          float acc[2][4] = {{0,0,0,0},{0,0,0,0}};
          tile_acc(sm.g.As, Wl + col, 3*D, tokg, acc);
          float bv[4]; *(float4*)bv = *(const float4*)(bl + col);
#pragma unroll
          for (int j = 0; j < 2; ++j) {
            float v[4];
#pragma unroll
            for (int c = 0; c < 4; ++c) v[c] = acc[j][c] + bv[c];
            *(float4*)(p.qkvb + (long)(tok0+tokg*2+j)*3*D + col) = *(float4*)v;
          }
        }
      }
      grid.sync();

      // ---- B: attention per (b,h) ----
      {
        const int d = tid & 63, g4 = tid >> 6;
        for (int bh = wgid; bh < BATCH*NH; bh += nwg) {
          const int b = bh & 63, h = bh >> 6;
          __syncthreads();
          for (int s = g4; s < S; s += 4) {
            long base = (long)(s*BATCH + b)*(3*D) + h*HDIM + d;
            sm.a.qs[s*HDIM+d] = p.qkvb[base];
            sm.a.ks[s*HDIM+d] = p.qkvb[base + D];
            sm.a.vs[s*HDIM+d] = p.qkvb[base + 2*D];
          }
          __syncthreads();
          for (int q = tid; q < S*S; q += 256) {
            int si = q / S, ti = q - si*S;
            float acc = 0.f;
#pragma unroll 4
            for (int k = 0; k < HDIM; ++k) acc += sm.a.qs[si*HDIM+k] * sm.a.ks[ti*HDIM+k];
            sm.a.ps[si*(BPTT+1)+ti] = acc * 0.125f;   // 1/sqrt(64)
          }
          __syncthreads();
          if (tid < S) {
            float m = -1e30f;
            for (int t2 = 0; t2 < S; ++t2) m = fmaxf(m, sm.a.ps[tid*(BPTT+1)+t2]);
            float sum = 0.f;
            for (int t2 = 0; t2 < S; ++t2) {
              float e = expf(sm.a.ps[tid*(BPTT+1)+t2] - m);
              sm.a.ps[tid*(BPTT+1)+t2] = e; sum += e;
            }
            float inv = 1.0f/sum;
            for (int t2 = 0; t2 < S; ++t2) sm.a.ps[tid*(BPTT+1)+t2] *= inv;
          }
          __syncthreads();
          for (int s = g4; s < S; s += 4) {
            float acc = 0.f;
            for (int t2 = 0; t2 < S; ++t2) acc += sm.a.ps[s*(BPTT+1)+t2] * sm.a.vs[t2*HDIM+d];
            p.obuf[(long)(s*BATCH+b)*D + h*HDIM + d] = acc;
          }
        }
      }
      grid.sync();

      // ---- C: x = LN1(X + obuf @ Wo + bo)  (proj + LN fused; wave == one token pair) ----
      {
        const float* Wl  = p.Wo  + (long)l*D*D;
        const float* bol = p.bo  + l*D;
        const float* g1l = p.g1  + l*D;
        const float* be1l= p.be1 + l*D;
        const int col = colg*4;
        for (int t = wgid; t < ntok8; t += nwg) {
          const int tok0 = t*8;
          __syncthreads();
#pragma unroll
          for (int j = 0; j < 8; ++j) sm.g.As[j][tid] = p.obuf[(long)(tok0+j)*D + tid];
          __syncthreads();
          float acc[2][4] = {{0,0,0,0},{0,0,0,0}};
          tile_acc(sm.g.As, Wl + col, D, tokg, acc);
#pragma unroll
          for (int j = 0; j < 2; ++j) {
            const int tok = tok0 + tokg*2 + j;
            float v[4];
#pragma unroll
            for (int c = 0; c < 4; ++c) v[c] = acc[j][c] + X[(long)tok*D + col + c] + bol[col + c];
            float s = v[0]+v[1]+v[2]+v[3];
            for (int off = 32; off; off >>= 1) s += __shfl_down(s, off);
            float mu = __shfl(s, 0) * (1.0f/D);
            float q = 0.f;
#pragma unroll
            for (int c = 0; c < 4; ++c) { float dv = v[c]-mu; q += dv*dv; }
            for (int off = 32; off; off >>= 1) q += __shfl_down(q, off);
            float var = __shfl(q, 0) * (1.0f/D);
            float inv = 1.0f/sqrtf(var + 1e-5f);
#pragma unroll
            for (int c = 0; c < 4; ++c)
              p.xbuf[(long)tok*D + col + c] = (v[c]-mu)*inv*g1l[col+c] + be1l[col+c];
          }
        }
      }
      grid.sync();

      // ---- D: FF1+FF2 fused. tile (tx,ty): ff-slice kept in LDS, partial out -> pbuf[ty] ----
      {
        const float* W1l = p.W1 + (long)l*D*FFD;
        const float* b1l = p.b1 + l*FFD;
        const float* W2l = p.W2 + (long)l*FFD*D;
        const int col = colg*4;
        const int ntiles = ntok8*8;
        for (int t = wgid; t < ntiles; t += nwg) {
          const int tx = t % ntok8, ty = t / ntok8;
          const int tok0 = tx*8, fc0 = ty*256;
          __syncthreads();
#pragma unroll
          for (int j = 0; j < 8; ++j) sm.g.As[j][tid] = p.xbuf[(long)(tok0+j)*D + tid];
          __syncthreads();
          float acc[2][4] = {{0,0,0,0},{0,0,0,0}};
          tile_acc(sm.g.As, W1l + fc0 + col, FFD, tokg, acc);
#pragma unroll
          for (int j = 0; j < 2; ++j)
#pragma unroll
            for (int c = 0; c < 4; ++c)
              sm.g.ffs[tokg*2+j][col+c] = fmaxf(acc[j][c] + b1l[fc0+col+c], 0.f);
          __syncthreads();
          float acc2[2][4] = {{0,0,0,0},{0,0,0,0}};
          tile_acc(sm.g.ffs, W2l + (long)fc0*D + col, D, tokg, acc2);
#pragma unroll
          for (int j = 0; j < 2; ++j)
            *(float4*)(p.pbuf + ((long)ty*NMAX + tok0+tokg*2+j)*D + col) = *(float4*)acc2[j];
        }
      }
      grid.sync();

      // ---- E: x = LN2(x + sum(pbuf[0..7]) + b2)  (one token per wave, no LDS) ----
      {
        const float* b2l = p.b2 + l*D;
        const float* g2l = p.g2 + l*D;
        const float* be2l= p.be2 + l*D;
        const int c0 = colg*4;
        for (int tk = wgid*4 + tokg; tk < N; tk += nwg*4) {
          float v[4];
          *(float4*)v = *(const float4*)(p.xbuf + (long)tk*D + c0);
          float4 bb = *(const float4*)(b2l + c0);
          v[0]+=bb.x; v[1]+=bb.y; v[2]+=bb.z; v[3]+=bb.w;
#pragma unroll
          for (int q = 0; q < 8; ++q) {
            float4 pp = *(const float4*)(p.pbuf + ((long)q*NMAX + tk)*D + c0);
            v[0]+=pp.x; v[1]+=pp.y; v[2]+=pp.z; v[3]+=pp.w;
          }
          float s = v[0]+v[1]+v[2]+v[3];
          for (int off = 32; off; off >>= 1) s += __shfl_down(s, off);
          float mu = __shfl(s, 0) * (1.0f/D);
          float q2 = 0.f;
#pragma unroll
          for (int c = 0; c < 4; ++c) { float dv = v[c]-mu; q2 += dv*dv; }
          for (int off = 32; off; off >>= 1) q2 += __shfl_down(q2, off);
          float var = __shfl(q2, 0) * (1.0f/D);
          float inv = 1.0f/sqrtf(var + 1e-5f);
          float4 gg = *(const float4*)(g2l + c0);
          float4 ee = *(const float4*)(be2l + c0);
          float o[4];
          o[0]=(v[0]-mu)*inv*gg.x+ee.x; o[1]=(v[1]-mu)*inv*gg.y+ee.y;
          o[2]=(v[2]-mu)*inv*gg.z+ee.z; o[3]=(v[3]-mu)*inv*gg.w+ee.w;
          *(float4*)(p.xbuf + (long)tk*D + c0) = *(float4*)o;
        }
      }
      grid.sync();
    } // layers

    // ---- F: logits = xbuf[last 64 rows] @ W_out + b_out ----
    {
      const float* A = p.xbuf + (long)i*BATCH*D;
      const int ntiles = 8 * ((VOC + 255) >> 8);   // 8 x 118
      for (int t = wgid; t < ntiles; t += nwg) {
        const int tx = t & 7, ty = t >> 3;
        const int tok0 = tx*8;
        const int col = ty*256 + colg*4;
        const int colL = col > VOC-4 ? VOC-4 : col;
        __syncthreads();
#pragma unroll
        for (int j = 0; j < 8; ++j) sm.g.As[j][tid] = A[(long)(tok0+j)*D + tid];
        __syncthreads();
        float acc[2][4] = {{0,0,0,0},{0,0,0,0}};
        tile_acc(sm.g.As, p.W_out + colL, VOC, tokg, acc);
        if (col < VOC) {
          float bv[4]; *(float4*)bv = *(const float4*)(p.b_out + col);
#pragma unroll
          for (int j = 0; j < 2; ++j) {
            float v[4];
#pragma unroll
            for (int c = 0; c < 4; ++c) v[c] = acc[j][c] + bv[c];
            *(float4*)(p.logits + (long)(tok0+tokg*2+j)*VOC + col) = *(float4*)v;
          }
        }
      }
    }
    grid.sync();

    // ---- G: vocab softmax + argmax + outputs + next embed ----
    {
      for (int b = wgid; b < BATCH; b += nwg) {
        const float* lrow = p.logits + (long)b*VOC;
        __syncthreads();
        float m = -1e30f;
        for (int c = tid; c < VOC; c += 256) m = fmaxf(m, lrow[c]);
        for (int off = 32; off; off >>= 1) m = fmaxf(m, __shfl_down(m, off));
        if (colg == 0) sm.v.red[tokg] = m;
        __syncthreads();
        float gmax = fmaxf(fmaxf(sm.v.red[0],sm.v.red[1]), fmaxf(sm.v.red[2],sm.v.red[3]));
        __syncthreads();
        float s = 0.f, em = -1.0f; int ei = VOC;
        for (int c = tid; c < VOC; c += 256) {
          float e = expf(lrow[c] - gmax);
          s += e;
          if (e > em) { em = e; ei = c; }
        }
        for (int off = 32; off; off >>= 1) {
          float em2 = __shfl_down(em, off);
          int   ei2 = __shfl_down(ei, off);
          if (em2 > em || (em2 == em && ei2 < ei)) { em = em2; ei = ei2; }
          s += __shfl_down(s, off);
        }
        if (colg == 0) { sm.v.r_s[tokg] = s; sm.v.r_em[tokg] = em; sm.v.r_ei[tokg] = ei; }
        __syncthreads();
        float Ssum = sm.v.r_s[0]+sm.v.r_s[1]+sm.v.r_s[2]+sm.v.r_s[3];
        em = sm.v.r_em[0]; ei = sm.v.r_ei[0];
        for (int w = 1; w < 4; ++w)
          if (sm.v.r_em[w] > em || (sm.v.r_em[w] == em && sm.v.r_ei[w] < ei)) { em = sm.v.r_em[w]; ei = sm.v.r_ei[w]; }
        const int mk = p.maskb[b*BPTT + i];
        for (int c = tid; c < VOC; c += 256) {
          float prob = expf(lrow[c] - gmax) / Ssum;
          float* op = p.out_probs + (long)b*VOC + c;
          if (i == 0) *op = prob;              // mask[:,0] always 1
          else if (mk) *op = fmaxf(*op, prob);
          if (c == 2) p.out_eos[b*BPTT + i] = prob;
        }
        if (tid == 0) p.out_words[b*BPTT + i] = mk ? (float)ei : 0.0f;
        if (i + 1 < BPTT)
          p.embeds[(long)((i+1)*BATCH + b)*D + tid] = p.emb_table[(long)ei*D + tid];
      }
    }
    grid.sync();
  } // steps
}

// ---------------- host ----------------
extern "C" void kernel_launch(void* const* d_in, const int* in_sizes, int n_in,
                              void* d_out, int out_size, void* d_ws, size_t ws_size,
                              hipStream_t stream) {
  Params P;
  P.image_feats = (const float*)d_in[0];
  P.target      = (const int*)  d_in[1];
  P.emb_table   = (const float*)d_in[2];
  P.W_g2e       = (const float*)d_in[3];
  P.b_g2e       = (const float*)d_in[4];
  P.W_out       = (const float*)d_in[5];
  P.b_out       = (const float*)d_in[6];
  P.Wqkv        = (const float*)d_in[7];
  P.bqkv        = (const float*)d_in[8];
  P.Wo          = (const float*)d_in[9];
  P.bo          = (const float*)d_in[10];
  P.W1          = (const float*)d_in[11];
  P.b1          = (const float*)d_in[12];
  P.W2          = (const float*)d_in[13];
  P.b2          = (const float*)d_in[14];
  P.g1          = (const float*)d_in[15];
  P.be1         = (const float*)d_in[16];
  P.g2          = (const float*)d_in[17];
  P.be2         = (const float*)d_in[18];

  float* out_probs = (float*)d_out;
  P.out_probs = out_probs;
  P.out_words = out_probs + (long)BATCH*VOC;
  P.out_eos   = P.out_words + BATCH*BPTT;

  char* ws = (char*)d_ws;
  P.embeds = (float*)ws;  ws += sizeof(float)*(long)NMAX*D;
  P.xbuf   = (float*)ws;  ws += sizeof(float)*(long)NMAX*D;
  P.qkvb   = (float*)ws;  ws += sizeof(float)*(long)NMAX*3*D;
  P.obuf   = (float*)ws;  ws += sizeof(float)*(long)NMAX*D;
  P.pbuf   = (float*)ws;  ws += sizeof(float)*(long)8*NMAX*D;
  P.logits = (float*)ws;  ws += sizeof(float)*(long)BATCH*VOC;
  P.maskb  = (int*)ws;    ws += sizeof(int)*BATCH*BPTT;

  // persistent grid: occupancy-derived, capped at 4 blocks/CU (capture-safe host query)
  static int nwg = 0;
  if (nwg == 0) {
    int maxb = 0;
    hipOccupancyMaxActiveBlocksPerMultiprocessor(&maxb, mega, 256, 0);
    if (maxb < 1) maxb = 1;
    if (maxb > 4) maxb = 4;
    nwg = maxb * 256;   // 256 CUs on MI355X
  }
  void* args[] = { &P };
  hipError_t err = hipLaunchCooperativeKernel((void*)mega, dim3(nwg), dim3(256), args, 0, stream);
  if (err != hipSuccess && nwg > 256) {
    // conservative fallback: 1 block/CU is always co-resident at our LDS/VGPR footprint
    nwg = 256;
    hipLaunchCooperativeKernel((void*)mega, dim3(nwg), dim3(256), args, 0, stream);
  }
}

// Round 2
// 13886.935 us; speedup vs baseline: 2.1044x; 2.1044x over previous
//
#include <hip/hip_runtime.h>
#include <math.h>

#define D 256
#define NH 4
#define HDIM 64
#define FFD 2048
#define NL 3
#define VOC 30000
#define BPTT 20
#define BATCH 64
#define NMAX (BPTT*BATCH)   /* 1280 */
#define NCOLT 118           /* ceil(VOC/256) vocab column tiles */
#define TROWS 32            /* GEMM tile rows */
#define NWG 256

struct Params {
  const float* image_feats;
  const int*   target;
  const float* emb_table;
  const float* W_g2e; const float* b_g2e;
  const float* W_out; const float* b_out;
  const float* Wqkv; const float* bqkv;
  const float* Wo;   const float* bo;
  const float* W1;   const float* b1;
  const float* W2;   const float* b2;
  const float* g1;   const float* be1;
  const float* g2;   const float* be2;
  float* out_probs; float* out_words; float* out_eos;
  float* embeds; float* xbuf; float* qkvb0; float* qkvb; float* obuf;
  float* pbuf; float* logits;
  float* pm; float* pd; float* pv; float* gS;
  int* pi; int* maskS;
  unsigned* barrier;
};

// ---- device-coherent (cross-XCD) scalar access: bypass non-coherent L2 ----
__device__ __forceinline__ float cld(const float* p) {
  return __hip_atomic_load(p, __ATOMIC_RELAXED, __HIP_MEMORY_SCOPE_AGENT);
}
__device__ __forceinline__ void cst(float* p, float v) {
  __hip_atomic_store(p, v, __ATOMIC_RELAXED, __HIP_MEMORY_SCOPE_AGENT);
}
__device__ __forceinline__ int cldi(const int* p) {
  return __hip_atomic_load(p, __ATOMIC_RELAXED, __HIP_MEMORY_SCOPE_AGENT);
}
__device__ __forceinline__ void csti(int* p, int v) {
  __hip_atomic_store(p, v, __ATOMIC_RELAXED, __HIP_MEMORY_SCOPE_AGENT);
}

// ---- grid barrier: monotonic counter, relaxed agent atomics, NO L2 flush ----
// Correct because all cross-block data uses cld/cst (already at LLC once vmcnt
// drains, which __syncthreads does for every wave).
__device__ __forceinline__ void gbar(unsigned* cnt, unsigned target) {
  asm volatile("s_waitcnt vmcnt(0) lgkmcnt(0)" ::: "memory");
  __syncthreads();
  if (threadIdx.x == 0) {
    __hip_atomic_fetch_add(cnt, 1u, __ATOMIC_RELAXED, __HIP_MEMORY_SCOPE_AGENT);
    while (__hip_atomic_load(cnt, __ATOMIC_RELAXED, __HIP_MEMORY_SCOPE_AGENT) < target)
      __builtin_amdgcn_s_sleep(2);
  }
  __syncthreads();
  asm volatile("" ::: "memory");
}

// ---- stage 32 rows x 256 features into LDS (coherent source) ----
__device__ __forceinline__ void stage32(float (*As)[D], const float* src, long row0) {
  const int tid = threadIdx.x;
#pragma unroll 4
  for (int j = 0; j < TROWS; ++j)
    As[j][tid] = cld(src + (row0 + j)*(long)D + tid);
}

// ---- 32x256 @ 256xM tile: thread (colg,tokg) -> rows tokg*8+j, cols col..col+3
// As reads are wave-broadcast (same addr all lanes) -> conflict-free.
__device__ __forceinline__ void mm32(const float (*As)[D], const float* __restrict__ Wp,
                                     int M, float acc[8][4]) {
  const int r0 = (threadIdx.x >> 6) * 8;
  for (int kk = 0; kk < D; kk += 4) {
    float w[4][4];
#pragma unroll
    for (int q = 0; q < 4; ++q)
      *(float4*)w[q] = *(const float4*)(Wp + (long)(kk+q)*M);
#pragma unroll
    for (int j = 0; j < 8; ++j) {
      float a[4];
      *(float4*)a = *(const float4*)&As[r0+j][kk];
#pragma unroll
      for (int c = 0; c < 4; ++c)
#pragma unroll
        for (int q = 0; q < 4; ++q)
          acc[j][c] += a[q]*w[q][c];
    }
  }
}

__global__ __launch_bounds__(256) void mega(Params p) {
  extern __shared__ char smraw[];
  float (*As)[D] = (float(*)[D])smraw;                     // 32KB
  float (*Bs)[D] = (float(*)[D])(smraw + TROWS*D*4);       // 32KB
  const int tid = threadIdx.x, wgid = blockIdx.x, nwg = gridDim.x;
  const int colg = tid & 63, tokg = tid >> 6;
  unsigned bars = 0;
  unsigned* cnt = p.barrier;

  // ================= init: img embed (blocks 0..63) =================
  if (wgid < BATCH) {
    float* xs = (float*)smraw;
    int b = wgid;
    for (int j = 0; j < 8; ++j) xs[tid + j*256] = p.image_feats[b*2048 + tid + j*256];
    __syncthreads();
    float acc = 0.f;
    for (int k = 0; k < 2048; k += 4) {
      float4 xv = *(const float4*)&xs[k];
      acc += xv.x * p.W_g2e[(k+0)*D + tid];
      acc += xv.y * p.W_g2e[(k+1)*D + tid];
      acc += xv.z * p.W_g2e[(k+2)*D + tid];
      acc += xv.w * p.W_g2e[(k+3)*D + tid];
    }
    cst(&p.embeds[(long)b*D + tid], acc + p.b_g2e[tid]);
  }
  gbar(cnt, ++bars * nwg);

  // ================= decode loop =================
  for (int i = 0; i < BPTT; ++i) {
    const int S = i + 1, N = S * BATCH;

    // ---- PH1: A0 (layer-0 qkv for NEW position only; cached across steps)
    //          blocks 118..123. || H(i-1): out_probs update, blocks 0..117.
    if (wgid >= NCOLT && wgid < NCOLT + 6) {
      int idx = wgid - NCOLT;
      int tt = idx & 1, cp = idx >> 1;
      long row0 = (long)i*BATCH + tt*TROWS;
      stage32(As, p.embeds, row0);
      __syncthreads();
      float acc[8][4] = {};
      int col = cp*256 + colg*4;
      mm32(As, p.Wqkv + col, 3*D, acc);
      float bv[4]; *(float4*)bv = *(const float4*)(p.bqkv + col);
      for (int j = 0; j < 8; ++j) {
        long row = row0 + tokg*8 + j;
        for (int c = 0; c < 4; ++c)
          cst(&p.qkvb0[row*(3*D) + col + c], acc[j][c] + bv[c]);
      }
    } else if (wgid < NCOLT && i > 0) {
      float* gm = (float*)smraw; float* ss = gm + 64; int* mk = (int*)(ss + 64);
      if (tid < 64) {
        gm[tid] = cld(&p.gS[tid*2]); ss[tid] = cld(&p.gS[tid*2+1]);
        mk[tid] = cldi(&p.maskS[tid]);
      }
      __syncthreads();
      int col = wgid*256 + colg*4;
      if (col < VOC) {
        for (int j = 0; j < 16; ++j) {
          int b = tokg*16 + j;
          if (i-1 == 0 || mk[b]) {
            for (int c = 0; c < 4; ++c) {
              float l = cld(&p.logits[(long)b*VOC + col + c]);
              float pr = expf(l - gm[b]) / ss[b];
              float* op = &p.out_probs[(long)b*VOC + col + c];
              if (i-1 == 0) *op = pr; else *op = fmaxf(*op, pr);
            }
          }
        }
      }
    }
    gbar(cnt, ++bars * nwg);

    for (int l = 0; l < NL; ++l) {
      // ---- B: attention, block = (b,h), 256 blocks exactly ----
      {
        const float* src = (l == 0) ? p.qkvb0 : p.qkvb;
        float* qs = (float*)smraw;
        float* ks = qs + BPTT*HDIM;
        float* vs = ks + BPTT*HDIM;
        float* ps = vs + BPTT*HDIM;
        int b = wgid & 63, h = wgid >> 6;
        int d = tid & 63, g4 = tid >> 6;
        for (int s = g4; s < S; s += 4) {
          long base = (long)(s*BATCH + b)*(3*D) + h*HDIM + d;
          qs[s*HDIM+d] = cld(&src[base]);
          ks[s*HDIM+d] = cld(&src[base + D]);
          vs[s*HDIM+d] = cld(&src[base + 2*D]);
        }
        __syncthreads();
        for (int q = tid; q < S*S; q += 256) {
          int si = q / S, ti = q - si*S;
          float acc = 0.f;
#pragma unroll 4
          for (int k = 0; k < HDIM; ++k) acc += qs[si*HDIM+k]*ks[ti*HDIM+k];
          ps[si*(BPTT+1)+ti] = acc * 0.125f;
        }
        __syncthreads();
        if (tid < S) {
          float m = -1e30f;
          for (int t2 = 0; t2 < S; ++t2) m = fmaxf(m, ps[tid*(BPTT+1)+t2]);
          float sum = 0.f;
          for (int t2 = 0; t2 < S; ++t2) {
            float e = expf(ps[tid*(BPTT+1)+t2] - m);
            ps[tid*(BPTT+1)+t2] = e; sum += e;
          }
          float inv = 1.f/sum;
          for (int t2 = 0; t2 < S; ++t2) ps[tid*(BPTT+1)+t2] *= inv;
        }
        __syncthreads();
        for (int s = g4; s < S; s += 4) {
          float acc = 0.f;
          for (int t2 = 0; t2 < S; ++t2) acc += ps[s*(BPTT+1)+t2]*vs[t2*HDIM+d];
          cst(&p.obuf[(long)(s*BATCH+b)*D + h*HDIM + d], acc);
        }
      }
      gbar(cnt, ++bars * nwg);

      // ---- C: proj + LN1 ; tiles = 2S (T=32) ----
      {
        const float* Xres = (l == 0) ? p.embeds : p.xbuf;
        const float* Wl = p.Wo + (long)l*D*D;
        const float* bol = p.bo + l*D;
        const float* g1l = p.g1 + l*D; const float* be1l = p.be1 + l*D;
        for (int t = wgid; t < 2*S; t += nwg) {
          long row0 = (long)t*TROWS;
          stage32(As, p.obuf, row0);
          __syncthreads();
          float acc[8][4] = {};
          int col = colg*4;
          mm32(As, Wl + col, D, acc);
          for (int j = 0; j < 8; ++j) {
            long tok = row0 + tokg*8 + j;
            float v[4];
            for (int c = 0; c < 4; ++c)
              v[c] = acc[j][c] + cld(&Xres[tok*D + col + c]) + bol[col + c];
            float s = v[0]+v[1]+v[2]+v[3];
            for (int off = 32; off; off >>= 1) s += __shfl_down(s, off);
            float mu = __shfl(s, 0) * (1.f/D);
            float q2 = 0.f;
            for (int c = 0; c < 4; ++c) { float dv = v[c]-mu; q2 += dv*dv; }
            for (int off = 32; off; off >>= 1) q2 += __shfl_down(q2, off);
            float var = __shfl(q2, 0) * (1.f/D);
            float inv = 1.f/sqrtf(var + 1e-5f);
            for (int c = 0; c < 4; ++c)
              cst(&p.xbuf[tok*D + col + c], (v[c]-mu)*inv*g1l[col+c] + be1l[col+c]);
          }
          __syncthreads();
        }
      }
      gbar(cnt, ++bars * nwg);

      // ---- D: ff1(relu)+ff2-partial per chunk; tiles = 16S (tt<2S, y<8) ----
      {
        const float* W1l = p.W1 + (long)l*D*FFD;
        const float* b1l = p.b1 + (long)l*FFD;
        const float* W2l = p.W2 + (long)l*FFD*D;
        for (int t = wgid; t < 16*S; t += nwg) {
          int tt = t % (2*S), y = t / (2*S);
          long row0 = (long)tt*TROWS;
          stage32(As, p.xbuf, row0);
          __syncthreads();
          float acc[8][4] = {};
          int fcol = y*256 + colg*4;
          mm32(As, W1l + fcol, FFD, acc);
          float bv[4]; *(float4*)bv = *(const float4*)(b1l + fcol);
          for (int j = 0; j < 8; ++j)
            for (int c = 0; c < 4; ++c)
              Bs[tokg*8+j][colg*4+c] = fmaxf(acc[j][c] + bv[c], 0.f);
          __syncthreads();
          float acc2[8][4] = {};
          int col = colg*4;
          mm32(Bs, W2l + (long)(y*256)*D + col, D, acc2);
          for (int j = 0; j < 8; ++j) {
            long tok = row0 + tokg*8 + j;
            for (int c = 0; c < 4; ++c)
              cst(&p.pbuf[((long)y*NMAX + tok)*D + col + c], acc2[j][c]);
          }
          __syncthreads();
        }
      }
      gbar(cnt, ++bars * nwg);

      // ---- E: x = LN2(x + sum(8 chunks) + b2) ; per-token waves ----
      {
        const float* b2l = p.b2 + l*D;
        const float* g2l = p.g2 + l*D; const float* be2l = p.be2 + l*D;
        for (long tk = wgid*4 + tokg; tk < N; tk += (long)nwg*4) {
          int c0 = colg*4;
          float v[4];
          for (int c = 0; c < 4; ++c) v[c] = cld(&p.xbuf[tk*D + c0 + c]) + b2l[c0+c];
          for (int y = 0; y < 8; ++y)
            for (int c = 0; c < 4; ++c)
              v[c] += cld(&p.pbuf[((long)y*NMAX + tk)*D + c0 + c]);
          float s = v[0]+v[1]+v[2]+v[3];
          for (int off = 32; off; off >>= 1) s += __shfl_down(s, off);
          float mu = __shfl(s, 0) * (1.f/D);
          float q2 = 0.f;
          for (int c = 0; c < 4; ++c) { float dv = v[c]-mu; q2 += dv*dv; }
          for (int off = 32; off; off >>= 1) q2 += __shfl_down(q2, off);
          float var = __shfl(q2, 0) * (1.f/D);
          float inv = 1.f/sqrtf(var + 1e-5f);
          for (int c = 0; c < 4; ++c)
            cst(&p.xbuf[tk*D + c0 + c], (v[c]-mu)*inv*g2l[c0+c] + be2l[c0+c]);
        }
      }
      gbar(cnt, ++bars * nwg);

      // ---- A(l+1): qkv for next layer ; tiles = 6S ----
      if (l + 1 < NL) {
        const float* Wl = p.Wqkv + (long)(l+1)*D*3*D;
        const float* bl = p.bqkv + (long)(l+1)*3*D;
        for (int t = wgid; t < 6*S; t += nwg) {
          int tt = t % (2*S), cp = t / (2*S);
          long row0 = (long)tt*TROWS;
          stage32(As, p.xbuf, row0);
          __syncthreads();
          float acc[8][4] = {};
          int col = cp*256 + colg*4;
          mm32(As, Wl + col, 3*D, acc);
          float bv[4]; *(float4*)bv = *(const float4*)(bl + col);
          for (int j = 0; j < 8; ++j) {
            long row = row0 + tokg*8 + j;
            for (int c = 0; c < 4; ++c)
              cst(&p.qkvb[row*(3*D) + col + c], acc[j][c] + bv[c]);
          }
          __syncthreads();
        }
        gbar(cnt, ++bars * nwg);
      }
    } // layers

    // ---- F: logits tiles (2 row-tiles x 118 col-tiles) + slice partials ----
    {
      long arow0 = (long)i*BATCH;
      for (int t = wgid; t < 2*NCOLT; t += nwg) {
        int rowt = t & 1, colt = t >> 1;
        stage32(As, p.xbuf, arow0 + rowt*TROWS);
        __syncthreads();
        int col = colt*256 + colg*4;
        int colL = col > VOC-4 ? VOC-4 : col;
        float acc[8][4] = {};
        mm32(As, p.W_out + colL, VOC, acc);
        float bv[4]; *(float4*)bv = *(const float4*)(p.b_out + colL);
        bool valid = (col < VOC);   // col,VOC both mult of 4
        for (int j = 0; j < 8; ++j) {
          int b = rowt*TROWS + tokg*8 + j;
          float v[4];
          float lm = -1e30f;
          for (int c = 0; c < 4; ++c) {
            v[c] = acc[j][c] + bv[c];
            if (valid) { cst(&p.logits[(long)b*VOC + col + c], v[c]); lm = fmaxf(lm, v[c]); }
          }
          float m = lm;
          for (int off = 32; off; off >>= 1) m = fmaxf(m, __shfl_down(m, off));
          m = __shfl(m, 0);
          float ls = 0.f;
          if (valid) for (int c = 0; c < 4; ++c) ls += expf(v[c] - m);
          for (int off = 32; off; off >>= 1) ls += __shfl_down(ls, off);
          float av = -1e30f; int ai = VOC;
          if (valid) for (int c = 0; c < 4; ++c) if (v[c] > av) { av = v[c]; ai = col + c; }
          for (int off = 32; off; off >>= 1) {
            float av2 = __shfl_down(av, off); int ai2 = __shfl_down(ai, off);
            if (av2 > av || (av2 == av && ai2 < ai)) { av = av2; ai = ai2; }
          }
          if (colg == 0) {
            int pidx = colt*64 + b;
            cst(&p.pm[pidx], m);
            cst(&p.pd[pidx], ls);
            cst(&p.pv[pidx], av);
            csti(&p.pi[pidx], ai);
          }
        }
        __syncthreads();
      }
    }
    gbar(cnt, ++bars * nwg);

    // ---- G: per-b merge of 118 slice partials; outputs + next embed ----
    if (wgid < BATCH) {
      int b = wgid;
      float* Lm = (float*)smraw;
      float* Ld = Lm + 128;
      float* Lv = Ld + 128;
      int*   Li = (int*)(Lv + 128);
      int*   Lei = Li + 128;
      if (tid < NCOLT) {
        Lm[tid] = cld(&p.pm[tid*64 + b]);
        Ld[tid] = cld(&p.pd[tid*64 + b]);
        Lv[tid] = cld(&p.pv[tid*64 + b]);
        Li[tid] = cldi(&p.pi[tid*64 + b]);
      }
      __syncthreads();
      if (tid == 0) {
        float gmax = -1e30f;
        for (int t2 = 0; t2 < NCOLT; ++t2) gmax = fmaxf(gmax, Lm[t2]);
        float Ssum = 0.f;
        for (int t2 = 0; t2 < NCOLT; ++t2) Ssum += Ld[t2] * expf(Lm[t2] - gmax);
        float bvv = -1e30f; int bi = VOC;
        for (int t2 = 0; t2 < NCOLT; ++t2)
          if (Lv[t2] > bvv || (Lv[t2] == bvv && Li[t2] < bi)) { bvv = Lv[t2]; bi = Li[t2]; }
        int run = 1;
        for (int j = 1; j <= i; ++j) if (p.target[b*BPTT + j] == 2) run = 0;
        float p2 = expf(cld(&p.logits[(long)b*VOC + 2]) - gmax) / Ssum;
        p.out_eos[b*BPTT + i] = p2;
        p.out_words[b*BPTT + i] = run ? (float)bi : 0.f;
        cst(&p.gS[b*2], gmax);
        cst(&p.gS[b*2+1], Ssum);
        csti(&p.maskS[b], run);
        Lei[0] = bi;
      }
      __syncthreads();
      if (i + 1 < BPTT) {
        int ei = Lei[0];
        cst(&p.embeds[((long)(i+1)*BATCH + b)*D + tid], p.emb_table[(long)ei*D + tid]);
      }
    }
    gbar(cnt, ++bars * nwg);
  } // steps

  // ---- final H: out_probs update for step 19 ----
  if (wgid < NCOLT) {
    float* gm = (float*)smraw; float* ss = gm + 64; int* mk = (int*)(ss + 64);
    if (tid < 64) {
      gm[tid] = cld(&p.gS[tid*2]); ss[tid] = cld(&p.gS[tid*2+1]);
      mk[tid] = cldi(&p.maskS[tid]);
    }
    __syncthreads();
    int col = wgid*256 + colg*4;
    if (col < VOC) {
      for (int j = 0; j < 16; ++j) {
        int b = tokg*16 + j;
        if (mk[b]) {
          for (int c = 0; c < 4; ++c) {
            float l = cld(&p.logits[(long)b*VOC + col + c]);
            float pr = expf(l - gm[b]) / ss[b];
            float* op = &p.out_probs[(long)b*VOC + col + c];
            *op = fmaxf(*op, pr);
          }
        }
      }
    }
  }
}

// ---------------- host ----------------
extern "C" void kernel_launch(void* const* d_in, const int* in_sizes, int n_in,
                              void* d_out, int out_size, void* d_ws, size_t ws_size,
                              hipStream_t stream) {
  Params P;
  P.image_feats = (const float*)d_in[0];
  P.target      = (const int*)  d_in[1];
  P.emb_table   = (const float*)d_in[2];
  P.W_g2e       = (const float*)d_in[3];
  P.b_g2e       = (const float*)d_in[4];
  P.W_out       = (const float*)d_in[5];
  P.b_out       = (const float*)d_in[6];
  P.Wqkv        = (const float*)d_in[7];
  P.bqkv        = (const float*)d_in[8];
  P.Wo          = (const float*)d_in[9];
  P.bo          = (const float*)d_in[10];
  P.W1          = (const float*)d_in[11];
  P.b1          = (const float*)d_in[12];
  P.W2          = (const float*)d_in[13];
  P.b2          = (const float*)d_in[14];
  P.g1          = (const float*)d_in[15];
  P.be1         = (const float*)d_in[16];
  P.g2          = (const float*)d_in[17];
  P.be2         = (const float*)d_in[18];

  float* out_probs = (float*)d_out;
  P.out_probs = out_probs;
  P.out_words = out_probs + (long)BATCH*VOC;
  P.out_eos   = P.out_words + BATCH*BPTT;

  char* ws = (char*)d_ws;
  P.embeds = (float*)ws;  ws += sizeof(float)*(long)NMAX*D;
  P.xbuf   = (float*)ws;  ws += sizeof(float)*(long)NMAX*D;
  P.qkvb0  = (float*)ws;  ws += sizeof(float)*(long)NMAX*3*D;
  P.qkvb   = (float*)ws;  ws += sizeof(float)*(long)NMAX*3*D;
  P.obuf   = (float*)ws;  ws += sizeof(float)*(long)NMAX*D;
  P.pbuf   = (float*)ws;  ws += sizeof(float)*(long)8*NMAX*D;
  P.logits = (float*)ws;  ws += sizeof(float)*(long)BATCH*VOC;
  P.pm     = (float*)ws;  ws += sizeof(float)*NCOLT*64;
  P.pd     = (float*)ws;  ws += sizeof(float)*NCOLT*64;
  P.pv     = (float*)ws;  ws += sizeof(float)*NCOLT*64;
  P.gS     = (float*)ws;  ws += sizeof(float)*128;
  P.pi     = (int*)ws;    ws += sizeof(int)*NCOLT*64;
  P.maskS  = (int*)ws;    ws += sizeof(int)*64;
  P.barrier= (unsigned*)ws; ws += sizeof(unsigned)*16;

  static bool inited = false;
  if (!inited) {
    hipFuncSetAttribute((const void*)mega,
                        hipFuncAttributeMaxDynamicSharedMemorySize, 65536);
    inited = true;
  }

  hipMemsetAsync(P.barrier, 0, 64, stream);
  void* args[] = { &P };
  hipError_t err = hipLaunchCooperativeKernel((void*)mega, dim3(NWG), dim3(256),
                                              args, 65536, stream);
  if (err != hipSuccess) {
    // 256 blocks x 64KB LDS = 1 block/CU on 256 CUs: co-resident by capacity.
    hipLaunchKernelGGL(mega, dim3(NWG), dim3(256), 65536, stream, P);
  }
}